// Round 1
// baseline (297.856 us; speedup 1.0000x reference)
//
#include <hip/hip_runtime.h>

typedef __attribute__((ext_vector_type(8))) short bf16x8;
typedef __attribute__((ext_vector_type(4))) float f32x4;
typedef __attribute__((ext_vector_type(8))) unsigned short ushort8;

#define N_BLADES 32
#define B_DIM 1024
#define IN_DIM 256
#define OUT_DIM 256
#define K_DIM (IN_DIM * N_BLADES)   // 8192
#define N_DIM (OUT_DIM * N_BLADES)  // 8192

// ---------- helpers ----------

__device__ __forceinline__ unsigned short f2bf(float f) {
    unsigned int u = __float_as_uint(f);
    u = (u + 0x7fff + ((u >> 16) & 1)) >> 16;   // RNE
    return (unsigned short)u;
}

// sign of e_a * e_b in Cl(4,1), replicating the reference bit-count
__device__ __forceinline__ float gp_sign(int a, int b) {
    int swaps = 0;
#pragma unroll
    for (int i = 0; i < 5; ++i) {
        int mask = (~((1 << (i + 1)) - 1)) & 31;
        swaps += ((b >> i) & 1) * __popc(a & mask);
    }
    float s = (swaps & 1) ? -1.0f : 1.0f;
    if (a & b & 16) s = -s;
    return s;
}

__device__ __forceinline__ void gload_lds16(const void* g, void* l) {
    __builtin_amdgcn_global_load_lds(
        (const __attribute__((address_space(1))) unsigned int*)g,
        (__attribute__((address_space(3))) unsigned int*)l, 16, 0, 0);
}

// ---------- prep 1: cast x fp32 -> bf16 ----------
__global__ __launch_bounds__(256) void cast_x_kernel(const float4* __restrict__ x,
                                                     unsigned short* __restrict__ xb) {
    int t = blockIdx.x * 256 + threadIdx.x;   // each thread: 8 elements
    float4 a = x[t * 2];
    float4 b = x[t * 2 + 1];
    ushort8 pk;
    pk[0] = f2bf(a.x); pk[1] = f2bf(a.y); pk[2] = f2bf(a.z); pk[3] = f2bf(a.w);
    pk[4] = f2bf(b.x); pk[5] = f2bf(b.y); pk[6] = f2bf(b.z); pk[7] = f2bf(b.w);
    *(ushort8*)(xb + (size_t)t * 8) = pk;
}

// ---------- prep 2: build w_g[(o,k)][(i,m')] = sign(m'^k, m') * w[o][i][m'^k], bf16 ----------
__global__ __launch_bounds__(256) void build_wg_kernel(const float* __restrict__ w,
                                                       unsigned short* __restrict__ wg) {
    __shared__ float sgn[1024];
    int tid = threadIdx.x;
    for (int idx = tid; idx < 1024; idx += 256) {
        sgn[idx] = gp_sign(idx >> 5, idx & 31);   // sgn[a*32+b] = sign(e_a, e_b)
    }
    __syncthreads();

    long t = (long)blockIdx.x * 256 + tid;  // octet id: 8.39M total
    int q   = (int)(t & 3);                 // m'-octet within row segment
    int i   = (int)((t >> 2) & 255);
    int row = (int)(t >> 10);               // o*32+k
    int k = row & 31;
    int o = row >> 5;
    int j = k & 7;
    int g = (q * 8) ^ (k & 24);             // source octet base

    const float4* w4 = (const float4*)(w + ((long)(o * 256 + i) * 32 + g));
    float4 va = w4[0], vb = w4[1];
    float v0[8] = {va.x, va.y, va.z, va.w, vb.x, vb.y, vb.z, vb.w};
    float v1[8], v2[8], v3[8];
#pragma unroll
    for (int e = 0; e < 8; ++e) v1[e] = (j & 4) ? v0[e ^ 4] : v0[e];
#pragma unroll
    for (int e = 0; e < 8; ++e) v2[e] = (j & 2) ? v1[e ^ 2] : v1[e];
#pragma unroll
    for (int e = 0; e < 8; ++e) v3[e] = (j & 1) ? v2[e ^ 1] : v2[e];
    // now v3[e] = w[o][i][(q*8+e)^k]

    ushort8 pk;
#pragma unroll
    for (int e = 0; e < 8; ++e) {
        int mp = q * 8 + e;        // m'
        int a  = mp ^ k;           // source blade m
        pk[e] = f2bf(v3[e] * sgn[a * 32 + mp]);
    }
    *(ushort8*)(wg + (long)row * K_DIM + i * 32 + q * 8) = pk;
}

// ---------- main GEMM: C[M=1024][N=8192] = A[M][K=8192] * Bt[N][K]^T  (bf16 in, fp32 out) ----------
#define BM 128
#define BN 128
#define BK 64

__global__ __launch_bounds__(256) void gemm_bt_kernel(const unsigned short* __restrict__ A,
                                                      const unsigned short* __restrict__ Bt,
                                                      float* __restrict__ C) {
    __shared__ unsigned short As[BM * BK];
    __shared__ unsigned short Bs[BN * BK];

    const int tid  = threadIdx.x;
    const int lane = tid & 63;
    const int wid  = tid >> 6;
    const int wr   = wid >> 1;     // wave row 0..1
    const int wc   = wid & 1;      // wave col 0..1

    const long row0 = (long)blockIdx.y * BM;
    const long col0 = (long)blockIdx.x * BN;

    f32x4 acc[4][4];
#pragma unroll
    for (int mi = 0; mi < 4; ++mi)
#pragma unroll
        for (int ni = 0; ni < 4; ++ni) acc[mi][ni] = (f32x4)0.0f;

    const char* Ag = (const char*)A;
    const char* Bg = (const char*)Bt;

    for (int k0 = 0; k0 < K_DIM; k0 += BK) {
        // stage A and B tiles: 16KB each, 4 issues of 16B per thread per tile
#pragma unroll
        for (int iss = 0; iss < 4; ++iss) {
            int ofs = iss * 4096 + tid * 16;    // linear byte offset in tile
            int r  = ofs >> 7;                  // row (128B per row)
            int cb = ofs & 127;                 // byte within row
            gload_lds16(Ag + (((row0 + r) * K_DIM + k0) * 2 + cb), (char*)As + ofs);
            gload_lds16(Bg + (((col0 + r) * K_DIM + k0) * 2 + cb), (char*)Bs + ofs);
        }
        asm volatile("s_waitcnt vmcnt(0)" ::: "memory");
        __syncthreads();

#pragma unroll
        for (int kk = 0; kk < 2; ++kk) {
            bf16x8 a[4], b[4];
#pragma unroll
            for (int mi = 0; mi < 4; ++mi) {
                int r = wr * 64 + mi * 16 + (lane & 15);
                a[mi] = *(const bf16x8*)&As[r * BK + kk * 32 + (lane >> 4) * 8];
            }
#pragma unroll
            for (int ni = 0; ni < 4; ++ni) {
                int c = wc * 64 + ni * 16 + (lane & 15);
                b[ni] = *(const bf16x8*)&Bs[c * BK + kk * 32 + (lane >> 4) * 8];
            }
#pragma unroll
            for (int mi = 0; mi < 4; ++mi)
#pragma unroll
                for (int ni = 0; ni < 4; ++ni)
                    acc[mi][ni] = __builtin_amdgcn_mfma_f32_16x16x32_bf16(
                        a[mi], b[ni], acc[mi][ni], 0, 0, 0);
        }
        __syncthreads();
    }

    // epilogue: C/D layout col=lane&15, row=(lane>>4)*4+j (m89-verified)
    const int cr = (lane >> 4) * 4;
    const int cc = lane & 15;
#pragma unroll
    for (int mi = 0; mi < 4; ++mi)
#pragma unroll
        for (int ni = 0; ni < 4; ++ni)
#pragma unroll
            for (int j = 0; j < 4; ++j) {
                long r = row0 + wr * 64 + mi * 16 + cr + j;
                long c = col0 + wc * 64 + ni * 16 + cc;
                C[r * N_DIM + c] = acc[mi][ni][j];
            }
}

// ---------- fallback (ws too small): direct fp32, correct but slow ----------
__global__ __launch_bounds__(256) void fallback_gp_kernel(const float* __restrict__ x,
                                                          const float* __restrict__ w,
                                                          float* __restrict__ out) {
    __shared__ float xs[IN_DIM * 32];   // 32KB: x[b][*][*]
    __shared__ float tab[1024];         // tab[m*32+k] = sign(m, m^k)
    int tid = threadIdx.x;
    for (int idx = tid; idx < 1024; idx += 256) {
        int m = idx >> 5, k = idx & 31;
        tab[idx] = gp_sign(m, m ^ k);
    }
    int b = blockIdx.x;
    const float4* xrow = (const float4*)(x + (long)b * K_DIM);
    float4* xs4 = (float4*)xs;
    for (int idx = tid; idx < 2048; idx += 256) xs4[idx] = xrow[idx];
    __syncthreads();

    int wid = tid >> 6, lane = tid & 63;
    int o = blockIdx.y * 8 + wid;
    int k = lane & 31, half = lane >> 5;
    float acc = 0.f;
    const float* wrow = w + (long)o * K_DIM + half * 4096;
    for (int i = 0; i < 128; ++i) {
        int ib = (half * 128 + i) * 32;
#pragma unroll
        for (int m = 0; m < 32; ++m) {
            acc += xs[ib + (m ^ k)] * tab[m * 32 + k] * wrow[i * 32 + m];
        }
    }
    acc += __shfl_down(acc, 32);
    if (half == 0) out[((long)b * OUT_DIM + o) * 32 + k] = acc;
}

// ---------- launch ----------
extern "C" void kernel_launch(void* const* d_in, const int* in_sizes, int n_in,
                              void* d_out, int out_size, void* d_ws, size_t ws_size,
                              hipStream_t stream) {
    const float* x = (const float*)d_in[0];
    const float* w = (const float*)d_in[1];
    float* out = (float*)d_out;

    const size_t xb_elems = (size_t)B_DIM * K_DIM;        // 8.39M
    const size_t wg_elems = (size_t)N_DIM * K_DIM;        // 67.1M
    const size_t need = (xb_elems + wg_elems) * sizeof(unsigned short);  // ~151MB

    if (ws_size >= need) {
        unsigned short* xb = (unsigned short*)d_ws;
        unsigned short* wg = xb + xb_elems;

        cast_x_kernel<<<dim3(4096), dim3(256), 0, stream>>>((const float4*)x, xb);
        build_wg_kernel<<<dim3(32768), dim3(256), 0, stream>>>(w, wg);
        gemm_bt_kernel<<<dim3(N_DIM / BN, B_DIM / BM), dim3(256), 0, stream>>>(xb, wg, out);
    } else {
        fallback_gp_kernel<<<dim3(B_DIM, OUT_DIM / 8), dim3(256), 0, stream>>>(x, w, out);
    }
}

// Round 2
// 245.388 us; speedup vs baseline: 1.2138x; 1.2138x over previous
//
#include <hip/hip_runtime.h>

typedef __attribute__((ext_vector_type(8))) short bf16x8;
typedef __attribute__((ext_vector_type(4))) float f32x4;
typedef __attribute__((ext_vector_type(8))) unsigned short ushort8;

#define N_BLADES 32
#define B_DIM 1024
#define IN_DIM 256
#define OUT_DIM 256
#define K_DIM (IN_DIM * N_BLADES)   // 8192
#define N_DIM (OUT_DIM * N_BLADES)  // 8192

// ---------- helpers ----------

__device__ __forceinline__ unsigned short f2bf(float f) {
    unsigned int u = __float_as_uint(f);
    u = (u + 0x7fff + ((u >> 16) & 1)) >> 16;   // RNE
    return (unsigned short)u;
}

__device__ __forceinline__ float gp_sign(int a, int b) {
    int swaps = 0;
#pragma unroll
    for (int i = 0; i < 5; ++i) {
        int mask = (~((1 << (i + 1)) - 1)) & 31;
        swaps += ((b >> i) & 1) * __popc(a & mask);
    }
    float s = (swaps & 1) ? -1.0f : 1.0f;
    if (a & b & 16) s = -s;
    return s;
}

__device__ __forceinline__ void gload_lds16(const void* g, void* l) {
    __builtin_amdgcn_global_load_lds(
        (const __attribute__((address_space(1))) unsigned int*)g,
        (__attribute__((address_space(3))) unsigned int*)l, 16, 0, 0);
}

// ---------- prep 1: cast x fp32 -> bf16 (unchanged, known-good) ----------
__global__ __launch_bounds__(256) void cast_x_kernel(const float4* __restrict__ x,
                                                     unsigned short* __restrict__ xb) {
    int t = blockIdx.x * 256 + threadIdx.x;
    float4 a = x[t * 2];
    float4 b = x[t * 2 + 1];
    ushort8 pk;
    pk[0] = f2bf(a.x); pk[1] = f2bf(a.y); pk[2] = f2bf(a.z); pk[3] = f2bf(a.w);
    pk[4] = f2bf(b.x); pk[5] = f2bf(b.y); pk[6] = f2bf(b.z); pk[7] = f2bf(b.w);
    *(ushort8*)(xb + (size_t)t * 8) = pk;
}

// ---------- prep 2: build w_g (unchanged, known-good) ----------
__global__ __launch_bounds__(256) void build_wg_kernel(const float* __restrict__ w,
                                                       unsigned short* __restrict__ wg) {
    __shared__ float sgn[1024];
    int tid = threadIdx.x;
    for (int idx = tid; idx < 1024; idx += 256) {
        sgn[idx] = gp_sign(idx >> 5, idx & 31);
    }
    __syncthreads();

    long t = (long)blockIdx.x * 256 + tid;
    int q   = (int)(t & 3);
    int i   = (int)((t >> 2) & 255);
    int row = (int)(t >> 10);
    int k = row & 31;
    int o = row >> 5;
    int j = k & 7;
    int g = (q * 8) ^ (k & 24);

    const float4* w4 = (const float4*)(w + ((long)(o * 256 + i) * 32 + g));
    float4 va = w4[0], vb = w4[1];
    float v0[8] = {va.x, va.y, va.z, va.w, vb.x, vb.y, vb.z, vb.w};
    float v1[8], v2[8], v3[8];
#pragma unroll
    for (int e = 0; e < 8; ++e) v1[e] = (j & 4) ? v0[e ^ 4] : v0[e];
#pragma unroll
    for (int e = 0; e < 8; ++e) v2[e] = (j & 2) ? v1[e ^ 2] : v1[e];
#pragma unroll
    for (int e = 0; e < 8; ++e) v3[e] = (j & 1) ? v2[e ^ 1] : v2[e];

    ushort8 pk;
#pragma unroll
    for (int e = 0; e < 8; ++e) {
        int mp = q * 8 + e;
        int a  = mp ^ k;
        pk[e] = f2bf(v3[e] * sgn[a * 32 + mp]);
    }
    *(ushort8*)(wg + (long)row * K_DIM + i * 32 + q * 8) = pk;
}

// ---------- main GEMM: 8-phase schedule, BM=128 BN=256 BK=64, 8 waves (2Mx4N) ----------
// C[1024][8192] = A[1024][8192] * Bt[8192][8192]^T, bf16 in fp32 out.
// LDS: 3 buffers x (A 128x64 + B 256x64) bf16 = 3 x 48KB = 144KB, prefetch distance 2.
// Swizzle: byte ^= (row&7)<<4 on reads; global source pre-swizzled (involution).

#define TILE_ELEMS 24576           // (128+256)*64
#define A64 ((long)64 * K_DIM * 2) // byte stride of 64 rows
#define NT (K_DIM / 64)            // 128 K-tiles

#define FENCE() asm volatile("" ::: "memory")
#define BAR()   { FENCE(); __builtin_amdgcn_s_barrier(); FENCE(); }

__global__ __launch_bounds__(512, 2) void gemm8p_kernel(const unsigned short* __restrict__ A,
                                                        const unsigned short* __restrict__ Bt,
                                                        float* __restrict__ C) {
    __shared__ unsigned short lds[3 * TILE_ELEMS];

    const int tid  = threadIdx.x;
    const int lane = tid & 63;
    const int wid  = tid >> 6;
    const int wr   = wid >> 2;          // 0..1
    const int wc   = wid & 3;           // 0..3
    const int l15  = lane & 15;
    const int l4   = lane >> 4;
    const int swzf = (l15 & 7) << 4;    // read-side swizzle (== (row&7)<<4 for all frag rows)

    const long row0 = (long)blockIdx.y * 128;
    const long col0 = (long)blockIdx.x * 256;

    // staging constants (per thread): 8 threads per 128B row
    const int  rr    = tid >> 3;
    const int  tid16 = tid * 16;
    const int  scb   = ((tid & 7) * 16) ^ ((rr & 7) << 4);   // pre-swizzled source col byte
    const char* aSrc = (const char*)A  + (row0 + rr) * K_DIM * 2 + scb;
    const char* bSrc = (const char*)Bt + (col0 + rr) * K_DIM * 2 + scb;

    unsigned short* p0 = lds;                    // read buffer (tile t)
    unsigned short* p1 = lds + TILE_ELEMS;       // tile t+1
    unsigned short* p2 = lds + 2 * TILE_ELEMS;   // prefetch target (tile t+2)

#define STAGE_A(pbuf, gk) { \
    gload_lds16(aSrc + (gk),       (char*)(pbuf) + tid16); \
    gload_lds16(aSrc + A64 + (gk), (char*)(pbuf) + 8192 + tid16); }
#define STAGE_B2(pbuf, gk, j0) { \
    gload_lds16(bSrc + (j0)*A64 + (gk),     (char*)(pbuf) + 16384 + (j0)*8192 + tid16); \
    gload_lds16(bSrc + ((j0)+1)*A64 + (gk), (char*)(pbuf) + 16384 + ((j0)+1)*8192 + tid16); }

    f32x4 acc[4][4];
#pragma unroll
    for (int mi = 0; mi < 4; ++mi)
#pragma unroll
        for (int ni = 0; ni < 4; ++ni) acc[mi][ni] = (f32x4)0.0f;

    bf16x8 aF[2][2], bF[2][2];

#define READ_A(mh) \
    _Pragma("unroll") for (int u = 0; u < 2; ++u) \
    _Pragma("unroll") for (int kk = 0; kk < 2; ++kk) { \
        int r = wr * 64 + (mh) * 32 + u * 16 + l15; \
        aF[u][kk] = *(const bf16x8*)((const char*)p0 + r * 128 + ((kk * 64 + l4 * 16) ^ swzf)); }
#define READ_B(nh) \
    _Pragma("unroll") for (int v = 0; v < 2; ++v) \
    _Pragma("unroll") for (int kk = 0; kk < 2; ++kk) { \
        int r = wc * 64 + (nh) * 32 + v * 16 + l15; \
        bF[v][kk] = *(const bf16x8*)((const char*)p0 + 16384 + r * 128 + ((kk * 64 + l4 * 16) ^ swzf)); }
#define MFMA8(mh, nh) \
    _Pragma("unroll") for (int u = 0; u < 2; ++u) \
    _Pragma("unroll") for (int v = 0; v < 2; ++v) \
    _Pragma("unroll") for (int kk = 0; kk < 2; ++kk) \
        acc[(mh)*2+u][(nh)*2+v] = __builtin_amdgcn_mfma_f32_16x16x32_bf16( \
            aF[u][kk], bF[v][kk], acc[(mh)*2+u][(nh)*2+v], 0, 0, 0);

#define LGKM0()  asm volatile("s_waitcnt lgkmcnt(0)" ::: "memory")
#define VMC6()   asm volatile("s_waitcnt vmcnt(6)" ::: "memory")
#define PRIO1()  __builtin_amdgcn_s_setprio(1)
#define PRIO0()  __builtin_amdgcn_s_setprio(0)

    // prologue: stage tiles 0 (p0) and 1 (p1); wait tile 0
    STAGE_A(p0, 0); STAGE_B2(p0, 0, 0); STAGE_B2(p0, 0, 2);
    STAGE_A(p1, 128); STAGE_B2(p1, 128, 0); STAGE_B2(p1, 128, 2);
    VMC6();
    BAR();

    long kpre = 256;   // byte k-offset of tile t+2 (tile*128 bytes)
    for (int t = 0; t < NT; ++t) {
        // P0
        READ_A(0); READ_B(0);
        STAGE_A(p2, kpre);
        BAR(); LGKM0(); PRIO1(); MFMA8(0, 0); PRIO0(); BAR();
        // P1
        READ_B(1);
        STAGE_B2(p2, kpre, 0);
        BAR(); LGKM0(); PRIO1(); MFMA8(0, 1); PRIO0(); BAR();
        // P2
        READ_A(1);
        STAGE_B2(p2, kpre, 2);
        BAR(); LGKM0(); PRIO1(); MFMA8(1, 1); PRIO0(); BAR();
        // P3
        READ_B(0);
        BAR(); LGKM0(); PRIO1(); MFMA8(1, 0); PRIO0();
        VMC6();   // tile t+1 complete (t+2's 6 loads stay in flight)
        BAR();

        // rotate buffers, advance prefetch k (wraps to reload tiles 0/1 harmlessly)
        unsigned short* tmp = p0; p0 = p1; p1 = p2; p2 = tmp;
        kpre += 128;
        if (kpre == (long)NT * 128) kpre = 0;
    }

    // epilogue: C/D layout col=lane&15, row=(lane>>4)*4+j (m89-verified)
    const int cr = l4 * 4;
#pragma unroll
    for (int mi = 0; mi < 4; ++mi)
#pragma unroll
        for (int ni = 0; ni < 4; ++ni)
#pragma unroll
            for (int j = 0; j < 4; ++j) {
                long r = row0 + wr * 64 + mi * 16 + cr + j;
                long c = col0 + wc * 64 + ni * 16 + l15;
                C[r * N_DIM + c] = acc[mi][ni][j];
            }

#undef STAGE_A
#undef STAGE_B2
#undef READ_A
#undef READ_B
#undef MFMA8
}

// ---------- fallback (ws too small): direct fp32, correct but slow ----------
__global__ __launch_bounds__(256) void fallback_gp_kernel(const float* __restrict__ x,
                                                          const float* __restrict__ w,
                                                          float* __restrict__ out) {
    __shared__ float xs[IN_DIM * 32];
    __shared__ float tab[1024];
    int tid = threadIdx.x;
    for (int idx = tid; idx < 1024; idx += 256) {
        int m = idx >> 5, k = idx & 31;
        tab[idx] = gp_sign(m, m ^ k);
    }
    int b = blockIdx.x;
    const float4* xrow = (const float4*)(x + (long)b * K_DIM);
    float4* xs4 = (float4*)xs;
    for (int idx = tid; idx < 2048; idx += 256) xs4[idx] = xrow[idx];
    __syncthreads();

    int wid = tid >> 6, lane = tid & 63;
    int o = blockIdx.y * 8 + wid;
    int k = lane & 31, half = lane >> 5;
    float acc = 0.f;
    const float* wrow = w + (long)o * K_DIM + half * 4096;
    for (int i = 0; i < 128; ++i) {
        int ib = (half * 128 + i) * 32;
#pragma unroll
        for (int m = 0; m < 32; ++m) {
            acc += xs[ib + (m ^ k)] * tab[m * 32 + k] * wrow[i * 32 + m];
        }
    }
    acc += __shfl_down(acc, 32);
    if (half == 0) out[((long)b * OUT_DIM + o) * 32 + k] = acc;
}

// ---------- launch ----------
extern "C" void kernel_launch(void* const* d_in, const int* in_sizes, int n_in,
                              void* d_out, int out_size, void* d_ws, size_t ws_size,
                              hipStream_t stream) {
    const float* x = (const float*)d_in[0];
    const float* w = (const float*)d_in[1];
    float* out = (float*)d_out;

    const size_t xb_elems = (size_t)B_DIM * K_DIM;
    const size_t wg_elems = (size_t)N_DIM * K_DIM;
    const size_t need = (xb_elems + wg_elems) * sizeof(unsigned short);

    if (ws_size >= need) {
        unsigned short* xb = (unsigned short*)d_ws;
        unsigned short* wg = xb + xb_elems;

        cast_x_kernel<<<dim3(4096), dim3(256), 0, stream>>>((const float4*)x, xb);
        build_wg_kernel<<<dim3(32768), dim3(256), 0, stream>>>(w, wg);
        gemm8p_kernel<<<dim3(N_DIM / 256, B_DIM / 128), dim3(512), 0, stream>>>(xb, wg, out);
    } else {
        fallback_gp_kernel<<<dim3(B_DIM, OUT_DIM / 8), dim3(256), 0, stream>>>(x, w, out);
    }
}

// Round 3
// 242.243 us; speedup vs baseline: 1.2296x; 1.0130x over previous
//
#include <hip/hip_runtime.h>

typedef __attribute__((ext_vector_type(8))) short bf16x8;
typedef __attribute__((ext_vector_type(4))) float f32x4;
typedef __attribute__((ext_vector_type(8))) unsigned short ushort8;

#define N_BLADES 32
#define B_DIM 1024
#define IN_DIM 256
#define OUT_DIM 256
#define K_DIM (IN_DIM * N_BLADES)   // 8192
#define N_DIM (OUT_DIM * N_BLADES)  // 8192

// ---------- helpers ----------

__device__ __forceinline__ unsigned short f2bf(float f) {
    unsigned int u = __float_as_uint(f);
    u = (u + 0x7fff + ((u >> 16) & 1)) >> 16;   // RNE
    return (unsigned short)u;
}

__device__ __forceinline__ float gp_sign(int a, int b) {
    int swaps = 0;
#pragma unroll
    for (int i = 0; i < 5; ++i) {
        int mask = (~((1 << (i + 1)) - 1)) & 31;
        swaps += ((b >> i) & 1) * __popc(a & mask);
    }
    float s = (swaps & 1) ? -1.0f : 1.0f;
    if (a & b & 16) s = -s;
    return s;
}

__device__ __forceinline__ void gload_lds16(const void* g, void* l) {
    __builtin_amdgcn_global_load_lds(
        (const __attribute__((address_space(1))) unsigned int*)g,
        (__attribute__((address_space(3))) unsigned int*)l, 16, 0, 0);
}

// ---------- prep 1: cast x fp32 -> bf16 (unchanged, known-good) ----------
__global__ __launch_bounds__(256) void cast_x_kernel(const float4* __restrict__ x,
                                                     unsigned short* __restrict__ xb) {
    int t = blockIdx.x * 256 + threadIdx.x;
    float4 a = x[t * 2];
    float4 b = x[t * 2 + 1];
    ushort8 pk;
    pk[0] = f2bf(a.x); pk[1] = f2bf(a.y); pk[2] = f2bf(a.z); pk[3] = f2bf(a.w);
    pk[4] = f2bf(b.x); pk[5] = f2bf(b.y); pk[6] = f2bf(b.z); pk[7] = f2bf(b.w);
    *(ushort8*)(xb + (size_t)t * 8) = pk;
}

// ---------- prep 2: build w_g (unchanged, known-good) ----------
__global__ __launch_bounds__(256) void build_wg_kernel(const float* __restrict__ w,
                                                       unsigned short* __restrict__ wg) {
    __shared__ float sgn[1024];
    int tid = threadIdx.x;
    for (int idx = tid; idx < 1024; idx += 256) {
        sgn[idx] = gp_sign(idx >> 5, idx & 31);
    }
    __syncthreads();

    long t = (long)blockIdx.x * 256 + tid;
    int q   = (int)(t & 3);
    int i   = (int)((t >> 2) & 255);
    int row = (int)(t >> 10);
    int k = row & 31;
    int o = row >> 5;
    int j = k & 7;
    int g = (q * 8) ^ (k & 24);

    const float4* w4 = (const float4*)(w + ((long)(o * 256 + i) * 32 + g));
    float4 va = w4[0], vb = w4[1];
    float v0[8] = {va.x, va.y, va.z, va.w, vb.x, vb.y, vb.z, vb.w};
    float v1[8], v2[8], v3[8];
#pragma unroll
    for (int e = 0; e < 8; ++e) v1[e] = (j & 4) ? v0[e ^ 4] : v0[e];
#pragma unroll
    for (int e = 0; e < 8; ++e) v2[e] = (j & 2) ? v1[e ^ 2] : v1[e];
#pragma unroll
    for (int e = 0; e < 8; ++e) v3[e] = (j & 1) ? v2[e ^ 1] : v2[e];

    ushort8 pk;
#pragma unroll
    for (int e = 0; e < 8; ++e) {
        int mp = q * 8 + e;
        int a  = mp ^ k;
        pk[e] = f2bf(v3[e] * sgn[a * 32 + mp]);
    }
    *(ushort8*)(wg + (long)row * K_DIM + i * 32 + q * 8) = pk;
}

// ---------- main GEMM: 2-phase/K-tile, 16-MFMA clusters, BM=128 BN=256 BK=64 ----------
// C[1024][8192] = A[1024][8192] * Bt[8192][8192]^T, bf16 in fp32 out.
// LDS: 3 buffers x (A 128x64 + B 256x64) bf16 = 3 x 48KB = 144KB, prefetch distance 2.
// Swizzle: byte ^= (row&7)<<4 on reads; global source pre-swizzled (involution).
// Per K-tile per wave: 16 ds_read_b128, 32 MFMA, 4 barriers, vmcnt(6) once.

#define TILE_ELEMS 24576           // (128+256)*64
#define A64 ((long)64 * K_DIM * 2) // byte stride of 64 rows
#define NT (K_DIM / 64)            // 128 K-tiles

#define FENCE() asm volatile("" ::: "memory")
#define BAR()   { FENCE(); __builtin_amdgcn_s_barrier(); FENCE(); }

__global__ __launch_bounds__(512, 2) void gemm8p_kernel(const unsigned short* __restrict__ A,
                                                        const unsigned short* __restrict__ Bt,
                                                        float* __restrict__ C) {
    __shared__ unsigned short lds[3 * TILE_ELEMS];

    const int tid  = threadIdx.x;
    const int lane = tid & 63;
    const int wid  = tid >> 6;
    const int wr   = wid >> 2;          // 0..1
    const int wc   = wid & 3;           // 0..3
    const int l15  = lane & 15;
    const int l4   = lane >> 4;
    const int swzf = (l15 & 7) << 4;    // read-side swizzle (== (row&7)<<4 for all frag rows)

    const long row0 = (long)blockIdx.y * 128;
    const long col0 = (long)blockIdx.x * 256;

    // staging constants (per thread): 8 threads per 128B row
    const int  rr    = tid >> 3;
    const int  tid16 = tid * 16;
    const int  scb   = ((tid & 7) * 16) ^ ((rr & 7) << 4);   // pre-swizzled source col byte
    const char* aSrc = (const char*)A  + (row0 + rr) * K_DIM * 2 + scb;
    const char* bSrc = (const char*)Bt + (col0 + rr) * K_DIM * 2 + scb;

    unsigned short* p0 = lds;                    // read buffer (tile t)
    unsigned short* p1 = lds + TILE_ELEMS;       // tile t+1
    unsigned short* p2 = lds + 2 * TILE_ELEMS;   // prefetch target (tile t+2)

#define STAGE_A(pbuf, gk) { \
    gload_lds16(aSrc + (gk),       (char*)(pbuf) + tid16); \
    gload_lds16(aSrc + A64 + (gk), (char*)(pbuf) + 8192 + tid16); }
#define STAGE_B2(pbuf, gk, j0) { \
    gload_lds16(bSrc + (j0)*A64 + (gk),     (char*)(pbuf) + 16384 + (j0)*8192 + tid16); \
    gload_lds16(bSrc + ((j0)+1)*A64 + (gk), (char*)(pbuf) + 16384 + ((j0)+1)*8192 + tid16); }

    f32x4 acc[4][4];
#pragma unroll
    for (int mi = 0; mi < 4; ++mi)
#pragma unroll
        for (int ni = 0; ni < 4; ++ni) acc[mi][ni] = (f32x4)0.0f;

    bf16x8 aF[4][2];    // all 4 M-frags x 2 k-halves, read once per K-tile
    bf16x8 bF0[2][2];   // N-half 0
    bf16x8 bF1[2][2];   // N-half 1 (separate regs: no B re-read)

#define READ_A_ALL() \
    _Pragma("unroll") for (int mi = 0; mi < 4; ++mi) \
    _Pragma("unroll") for (int kk = 0; kk < 2; ++kk) { \
        int r = wr * 64 + mi * 16 + l15; \
        aF[mi][kk] = *(const bf16x8*)((const char*)p0 + r * 128 + ((kk * 64 + l4 * 16) ^ swzf)); }
#define READ_B0() \
    _Pragma("unroll") for (int v = 0; v < 2; ++v) \
    _Pragma("unroll") for (int kk = 0; kk < 2; ++kk) { \
        int r = wc * 64 + v * 16 + l15; \
        bF0[v][kk] = *(const bf16x8*)((const char*)p0 + 16384 + r * 128 + ((kk * 64 + l4 * 16) ^ swzf)); }
#define READ_B1() \
    _Pragma("unroll") for (int v = 0; v < 2; ++v) \
    _Pragma("unroll") for (int kk = 0; kk < 2; ++kk) { \
        int r = wc * 64 + 32 + v * 16 + l15; \
        bF1[v][kk] = *(const bf16x8*)((const char*)p0 + 16384 + r * 128 + ((kk * 64 + l4 * 16) ^ swzf)); }
#define MFMA16_H0() \
    _Pragma("unroll") for (int mi = 0; mi < 4; ++mi) \
    _Pragma("unroll") for (int v = 0; v < 2; ++v) \
    _Pragma("unroll") for (int kk = 0; kk < 2; ++kk) \
        acc[mi][v] = __builtin_amdgcn_mfma_f32_16x16x32_bf16( \
            aF[mi][kk], bF0[v][kk], acc[mi][v], 0, 0, 0);
#define MFMA16_H1() \
    _Pragma("unroll") for (int mi = 0; mi < 4; ++mi) \
    _Pragma("unroll") for (int v = 0; v < 2; ++v) \
    _Pragma("unroll") for (int kk = 0; kk < 2; ++kk) \
        acc[mi][2 + v] = __builtin_amdgcn_mfma_f32_16x16x32_bf16( \
            aF[mi][kk], bF1[v][kk], acc[mi][2 + v], 0, 0, 0);

#define LGKM0()  asm volatile("s_waitcnt lgkmcnt(0)" ::: "memory")
#define VMC6()   asm volatile("s_waitcnt vmcnt(6)" ::: "memory")
#define PRIO1()  __builtin_amdgcn_s_setprio(1)
#define PRIO0()  __builtin_amdgcn_s_setprio(0)

    // prologue: stage tiles 0 (p0) and 1 (p1); wait tile 0
    STAGE_A(p0, 0); STAGE_B2(p0, 0, 0); STAGE_B2(p0, 0, 2);
    STAGE_A(p1, 128); STAGE_B2(p1, 128, 0); STAGE_B2(p1, 128, 2);
    VMC6();
    BAR();

    long kpre = 256;   // byte k-offset of tile t+2 (tile*128 bytes)
    for (int t = 0; t < NT; ++t) {
        // PH0: 12 ds_read + 4 staging loads -> 16 MFMA
        READ_A_ALL();
        READ_B0();
        STAGE_A(p2, kpre);
        STAGE_B2(p2, kpre, 0);
        BAR(); LGKM0(); PRIO1(); MFMA16_H0(); PRIO0(); BAR();
        // PH1: 4 ds_read + 2 staging loads -> 16 MFMA
        READ_B1();
        STAGE_B2(p2, kpre, 2);
        BAR(); LGKM0(); PRIO1(); MFMA16_H1(); PRIO0();
        VMC6();   // tile t+1 complete (t+2's 6 loads stay in flight)
        BAR();

        // rotate buffers, advance prefetch k (wraps to reload tiles 0/1 harmlessly)
        unsigned short* tmp = p0; p0 = p1; p1 = p2; p2 = tmp;
        kpre += 128;
        if (kpre == (long)NT * 128) kpre = 0;
    }

    // epilogue: C/D layout col=lane&15, row=(lane>>4)*4+j (m89-verified)
    const int cr = l4 * 4;
#pragma unroll
    for (int mi = 0; mi < 4; ++mi)
#pragma unroll
        for (int ni = 0; ni < 4; ++ni)
#pragma unroll
            for (int j = 0; j < 4; ++j) {
                long r = row0 + wr * 64 + mi * 16 + cr + j;
                long c = col0 + wc * 64 + ni * 16 + l15;
                C[r * N_DIM + c] = acc[mi][ni][j];
            }

#undef STAGE_A
#undef STAGE_B2
#undef READ_A_ALL
#undef READ_B0
#undef READ_B1
#undef MFMA16_H0
#undef MFMA16_H1
}

// ---------- fallback (ws too small): direct fp32, correct but slow ----------
__global__ __launch_bounds__(256) void fallback_gp_kernel(const float* __restrict__ x,
                                                          const float* __restrict__ w,
                                                          float* __restrict__ out) {
    __shared__ float xs[IN_DIM * 32];
    __shared__ float tab[1024];
    int tid = threadIdx.x;
    for (int idx = tid; idx < 1024; idx += 256) {
        int m = idx >> 5, k = idx & 31;
        tab[idx] = gp_sign(m, m ^ k);
    }
    int b = blockIdx.x;
    const float4* xrow = (const float4*)(x + (long)b * K_DIM);
    float4* xs4 = (float4*)xs;
    for (int idx = tid; idx < 2048; idx += 256) xs4[idx] = xrow[idx];
    __syncthreads();

    int wid = tid >> 6, lane = tid & 63;
    int o = blockIdx.y * 8 + wid;
    int k = lane & 31, half = lane >> 5;
    float acc = 0.f;
    const float* wrow = w + (long)o * K_DIM + half * 4096;
    for (int i = 0; i < 128; ++i) {
        int ib = (half * 128 + i) * 32;
#pragma unroll
        for (int m = 0; m < 32; ++m) {
            acc += xs[ib + (m ^ k)] * tab[m * 32 + k] * wrow[i * 32 + m];
        }
    }
    acc += __shfl_down(acc, 32);
    if (half == 0) out[((long)b * OUT_DIM + o) * 32 + k] = acc;
}

// ---------- launch ----------
extern "C" void kernel_launch(void* const* d_in, const int* in_sizes, int n_in,
                              void* d_out, int out_size, void* d_ws, size_t ws_size,
                              hipStream_t stream) {
    const float* x = (const float*)d_in[0];
    const float* w = (const float*)d_in[1];
    float* out = (float*)d_out;

    const size_t xb_elems = (size_t)B_DIM * K_DIM;
    const size_t wg_elems = (size_t)N_DIM * K_DIM;
    const size_t need = (xb_elems + wg_elems) * sizeof(unsigned short);

    if (ws_size >= need) {
        unsigned short* xb = (unsigned short*)d_ws;
        unsigned short* wg = xb + xb_elems;

        cast_x_kernel<<<dim3(4096), dim3(256), 0, stream>>>((const float4*)x, xb);
        build_wg_kernel<<<dim3(32768), dim3(256), 0, stream>>>(w, wg);
        gemm8p_kernel<<<dim3(N_DIM / 256, B_DIM / 128), dim3(512), 0, stream>>>(xb, wg, out);
    } else {
        fallback_gp_kernel<<<dim3(B_DIM, OUT_DIM / 8), dim3(256), 0, stream>>>(x, w, out);
    }
}